// Round 8
// baseline (143.948 us; speedup 1.0000x reference)
//
#include <hip/hip_runtime.h>
#include <cstdint>
#include <cstring>
#include <vector>
#include <algorithm>

// CLOPLayer: out[b,c,k] = x[b,c, idx[k]], idx = seed-42-deterministic
// neighbor-swap permutation of the 224x224 grid (JAX threefry replicated
// bit-exactly on host at dlopen).
//
// R14: Ledger pattern across R6-R13: every FAST observation is
// single-direction HBM (fills 6.5 TB/s pure-write; R9 hot rep 14us =
// L3-read + NT-write; R12 probe 17us = L3-WARM read + write — never a cold
// mixed test). Every SLOW one (39-52us, six structures) mixes cold HBM reads
// with HBM writes (~4.2 TB/s aggregate). Theory: the cold-read+write MIX is
// the wall, not any kernel structure. Fix: phase separation via L3 —
// (1) sweep_x: pure-read prefetch of x (read-allocate into 256MB L3;
// 8 independent f4 loads/thread, asm-sunk), (2) unchanged R13 permute, whose
// stage reads now hit L3 (R9 hot rep measured this case: 14us).

#define PH 224
#define PW 224
#define PN (PH * PW)   // 50176
#define NBC (128 * 3)  // 384 (b,c) slices

#define R_OUT 32                    // output rows per tile
#define HALO 2
#define SR (R_OUT + 2 * HALO)       // 36 staged rows
#define SRPW (SR * PW)              // 8064 floats
#define NWIN (PH / R_OUT)           // 7 windows per slice
#define KWIN (R_OUT * PW)           // 7168 outputs per tile
#define TPB 512
#define EMIT_IT (KWIN / (2 * TPB))  // 7 float2 iterations per thread
#define STAGE_F4 (SR * (PW / 4))    // 2016 f4 stage loads
#define SITER ((STAGE_F4 + TPB - 1) / TPB)  // 4
#define OVF_CAP 1024                // per-window overflow slots (host-verified)

// Prefetch sweep geometry: 2352*256*8 = 4,816,896 f4 = exactly NBC*PN/4.
#define SWB 2352
#define SWT 256
#define SWSTRIDE ((size_t)SWB * SWT)  // 602112 f4

typedef float f4v __attribute__((ext_vector_type(4)));
typedef float f2v __attribute__((ext_vector_type(2)));

// ---------------------------------------------------------------------------
// Threefry-2x32, 20 rounds — bit-exact replica of jax/_src/prng.py lowering.
// ---------------------------------------------------------------------------
static inline uint32_t rotl32(uint32_t v, int d) {
  return (v << d) | (v >> (32 - d));
}

static void tf2x32(uint32_t k0, uint32_t k1, uint32_t x0, uint32_t x1,
                   uint32_t& o0, uint32_t& o1) {
  const uint32_t ks0 = k0, ks1 = k1, ks2 = k0 ^ k1 ^ 0x1BD11BDAu;
  uint32_t v0 = x0 + ks0;
  uint32_t v1 = x1 + ks1;
  static const int ra[4] = {13, 15, 26, 6};
  static const int rb[4] = {17, 29, 16, 24};
#define R4X(rr)                             \
  do {                                      \
    for (int _i = 0; _i < 4; ++_i) {        \
      v0 += v1;                             \
      v1 = rotl32(v1, (rr)[_i]);            \
      v1 ^= v0;                             \
    }                                       \
  } while (0)
  R4X(ra); v0 += ks1; v1 += ks2 + 1u;
  R4X(rb); v0 += ks2; v1 += ks0 + 2u;
  R4X(ra); v0 += ks0; v1 += ks1 + 3u;
  R4X(rb); v0 += ks1; v1 += ks2 + 4u;
  R4X(ra); v0 += ks2; v1 += ks0 + 5u;
#undef R4X
  o0 = v0;
  o1 = v1;
}

static void jax_split2(uint32_t k0, uint32_t k1,
                       uint32_t& a0, uint32_t& a1, uint32_t& b0, uint32_t& b1) {
  tf2x32(k0, k1, 0u, 0u, a0, a1);
  tf2x32(k0, k1, 0u, 1u, b0, b1);
}

static inline uint32_t jax_rb32(uint32_t k0, uint32_t k1, uint32_t i) {
  uint32_t y0, y1;
  tf2x32(k0, k1, 0u, i, y0, y1);
  return y0 ^ y1;  // partitionable random_bits: bits1 ^ bits2
}

// ---------------------------------------------------------------------------
// Host-side bit-exact replication of _index_permute(jax.random.key(42), ...)
// ---------------------------------------------------------------------------
static std::vector<int> compute_perm() {
  const int n = PN;
  const uint32_t K0 = 0u, K1 = 42u;  // jax.random.key(42)

  uint32_t k1a, k1b, k2a, k2b;
  jax_split2(K0, K1, k1a, k1b, k2a, k2b);

  // order = permutation(k1, n): 2 rounds of stable sort by random_bits.
  std::vector<int> order(n);
  for (int i = 0; i < n; ++i) order[i] = i;
  uint32_t ck0 = k1a, ck1 = k1b;
  std::vector<std::pair<uint32_t, int>> kv(n);
  for (int round = 0; round < 2; ++round) {
    uint32_t nk0, nk1, sk0, sk1;
    jax_split2(ck0, ck1, nk0, nk1, sk0, sk1);
    ck0 = nk0; ck1 = nk1;
    for (int i = 0; i < n; ++i) {
      kv[i] = {jax_rb32(sk0, sk1, (uint32_t)i), order[i]};
    }
    std::stable_sort(kv.begin(), kv.end(),
                     [](const std::pair<uint32_t, int>& a,
                        const std::pair<uint32_t, int>& b) {
                       return a.first < b.first;
                     });
    for (int i = 0; i < n; ++i) order[i] = kv[i].second;
  }

  // rs = choice(k2, 5, (n,), p): fp32 cumsum + uniform + searchsorted(left).
  float probs[5] = {(float)(1.0 - 0.3), (float)(0.3 / 4), (float)(0.3 / 4),
                    (float)(0.3 / 4), (float)(0.3 / 4)};
  float pc[5];
  pc[0] = probs[0];
  for (int i = 1; i < 5; ++i) pc[i] = pc[i - 1] + probs[i];

  std::vector<uint8_t> rs(n);
  for (int i = 0; i < n; ++i) {
    uint32_t bits = jax_rb32(k2a, k2b, (uint32_t)i);
    uint32_t fb = (bits >> 9) | 0x3f800000u;
    float u;
    std::memcpy(&u, &fb, 4);
    u -= 1.0f;
    if (u < 0.0f) u = 0.0f;
    float r = pc[4] * (1.0f - u);
    int ind = (int)(std::lower_bound(pc, pc + 5, r) - pc);
    rs[i] = (uint8_t)ind;
  }

  // Sequential swap scan.
  std::vector<int> idx(n);
  for (int i = 0; i < n; ++i) idx[i] = i;
  for (int t = 0; t < n; ++t) {
    const int id = order[t];
    const int r = rs[t];
    const int i = id / PW, j = id % PW;
    int ip = i, jp = j;
    if (r == 1)      ip = (i + 1) % PH;
    else if (r == 2) ip = (i - 1 + PH) % PH;
    else if (r == 3) jp = (j + 1) % PW;
    else if (r == 4) jp = (j - 1 + PW) % PW;
    const int id2 = (r == 0) ? id : (ip * PW + jp);
    const int a = idx[id];
    const int b = idx[id2];
    idx[id]  = b;
    idx[id2] = a;
  }
  return idx;
}

// Build per-window LDS offset tables (halo=2). Sources whose toroidal row
// distance exceeds the halo go to a per-window overflow list (staged into
// LDS spill slots at SRPW + o). Returns false iff any window overflows cap.
static bool build_tables(const std::vector<int>& idx,
                         std::vector<uint16_t>& lofs, std::vector<int>& ovf,
                         std::vector<int>& cnt) {
  lofs.assign((size_t)NWIN * KWIN, 0);
  ovf.assign((size_t)NWIN * OVF_CAP, 0);
  cnt.assign(NWIN, 0);
  for (int w = 0; w < NWIN; ++w) {
    const int g0 = w * R_OUT - HALO;
    int no = 0;
    for (int kk = 0; kk < KWIN; ++kk) {
      const int k = w * KWIN + kk;
      const int s = idx[k];
      const int srow = s / PW, scol = s % PW;
      int i = ((srow - g0) % PH + PH) % PH;
      if (i < SR) {
        lofs[(size_t)w * KWIN + kk] = (uint16_t)(i * PW + scol);
      } else {
        if (no >= OVF_CAP) return false;
        ovf[(size_t)w * OVF_CAP + no] = s;
        lofs[(size_t)w * KWIN + kk] = (uint16_t)(SRPW + no);
        ++no;
      }
    }
    cnt[w] = no;
  }
  return true;
}

// Load-time init (legal: runs at dlopen, before graph capture).
struct PermHolder {
  std::vector<int> h_idx;
  int* d_idx = nullptr;
  uint16_t* d_lofs = nullptr;
  int* d_ovf = nullptr;
  int* d_cnt = nullptr;
  bool lds_ok = false;

  PermHolder() {
    h_idx = compute_perm();

    int* p = nullptr;
    if (hipMalloc(&p, PN * sizeof(int)) == hipSuccess &&
        hipMemcpy(p, h_idx.data(), PN * sizeof(int),
                  hipMemcpyHostToDevice) == hipSuccess) {
      d_idx = p;
    }

    std::vector<uint16_t> lofs;
    std::vector<int> ovf, cnt;
    if (build_tables(h_idx, lofs, ovf, cnt)) {
      uint16_t* ql = nullptr;
      int* qo = nullptr;
      int* qc = nullptr;
      bool ok =
          hipMalloc(&ql, lofs.size() * sizeof(uint16_t)) == hipSuccess &&
          hipMemcpy(ql, lofs.data(), lofs.size() * sizeof(uint16_t),
                    hipMemcpyHostToDevice) == hipSuccess &&
          hipMalloc(&qo, ovf.size() * sizeof(int)) == hipSuccess &&
          hipMemcpy(qo, ovf.data(), ovf.size() * sizeof(int),
                    hipMemcpyHostToDevice) == hipSuccess &&
          hipMalloc(&qc, cnt.size() * sizeof(int)) == hipSuccess &&
          hipMemcpy(qc, cnt.data(), cnt.size() * sizeof(int),
                    hipMemcpyHostToDevice) == hipSuccess;
      if (ok) {
        d_lofs = ql;
        d_ovf = qo;
        d_cnt = qc;
        lds_ok = true;
      }
    }
  }
};
static PermHolder g_perm;

// ---------------------------------------------------------------------------
// Prefetch sweep: pure-read pass over x; values asm-sunk (no DCE, no store).
// Regular (cached) loads read-allocate x into L3 so the permute's stage
// reads hit cache. 8 independent f4 loads per thread = deep MLP.
// ---------------------------------------------------------------------------
__global__ __launch_bounds__(SWT) void sweep_x(const f4v* __restrict__ x) {
  const size_t i0 = (size_t)blockIdx.x * SWT + threadIdx.x;
  f4v a0 = x[i0];
  f4v a1 = x[i0 + SWSTRIDE];
  f4v a2 = x[i0 + 2 * SWSTRIDE];
  f4v a3 = x[i0 + 3 * SWSTRIDE];
  f4v a4 = x[i0 + 4 * SWSTRIDE];
  f4v a5 = x[i0 + 5 * SWSTRIDE];
  f4v a6 = x[i0 + 6 * SWSTRIDE];
  f4v a7 = x[i0 + 7 * SWSTRIDE];
  f4v s = a0 + a1 + a2 + a3 + a4 + a5 + a6 + a7;
  asm volatile("" ::"v"(s.x), "v"(s.y), "v"(s.z), "v"(s.w));
}

// ---------------------------------------------------------------------------
// LDS permute, glds staging (unchanged R13). blockIdx.x = window (7),
// blockIdx.y = bc (384). 36.4KB LDS -> 4 blocks/CU.
// ---------------------------------------------------------------------------
__global__ __launch_bounds__(TPB) void clop_glds(
    const float* __restrict__ x, const uint16_t* __restrict__ lofs,
    const int* __restrict__ ovf_idx, const int* __restrict__ ovf_cnt,
    float* __restrict__ out) {
  __shared__ float tile[SRPW + OVF_CAP];  // 36352 B -> 4 blocks/CU

  const int w = blockIdx.x;
  const size_t bc = blockIdx.y;
  const int g0 = w * R_OUT - HALO;
  const float* xs = x + bc * PN;

  // Stage: dense f4 rows straight to LDS (fire-and-forget glds).
#pragma unroll
  for (int i = 0; i < SITER; ++i) {
    const int t = (int)threadIdx.x + i * TPB;
    if (t < STAGE_F4) {
      const int r = t / (PW / 4);
      const int j = (t % (PW / 4)) * 4;
      int g = g0 + r;
      if (g < 0) g += PH;
      else if (g >= PH) g -= PH;
      __builtin_amdgcn_global_load_lds(
          (const __attribute__((address_space(1))) void*)(xs + g * PW + j),
          (__attribute__((address_space(3))) void*)(tile + (size_t)t * 4),
          16, 0, 0);
    }
  }

  // Emit-offset prefetch (independent; overlaps glds latency).
  const uint32_t* lw2 = (const uint32_t*)(lofs + (size_t)w * KWIN);
  uint32_t o2[EMIT_IT];
#pragma unroll
  for (int i = 0; i < EMIT_IT; ++i)
    o2[i] = lw2[i * TPB + (int)threadIdx.x];

  // Overflow spill: rare far-movers, 4B glds into LDS slots.
  const int novf = ovf_cnt[w];
  for (int t = (int)threadIdx.x; t < novf; t += TPB) {
    const int s = ovf_idx[w * OVF_CAP + t];
    __builtin_amdgcn_global_load_lds(
        (const __attribute__((address_space(1))) void*)(xs + s),
        (__attribute__((address_space(3))) void*)(tile + SRPW + t), 4, 0, 0);
  }

  __syncthreads();  // drains vmcnt(0) lgkmcnt(0) + barrier

  // Emit: 7 x float2 interleaved per thread (8B lane stride, 2-way banks =
  // free); dense 512B/wave NT stores (R12: cached stores were worse).
  float* ob = out + bc * PN + (size_t)w * KWIN;
#pragma unroll
  for (int i = 0; i < EMIT_IT; ++i) {
    const uint32_t o = o2[i];
    f2v v;
    v.x = tile[o & 0xFFFFu];
    v.y = tile[o >> 16];
    __builtin_nontemporal_store(
        v, (f2v*)(ob + i * (2 * TPB) + 2 * (int)threadIdx.x));
  }
}

// ---------------------------------------------------------------------------
// Fallback (proven-correct R10 kernel): copy-structured f4 gather.
// ---------------------------------------------------------------------------
__global__ __launch_bounds__(256) void clop_gather4(
    const float* __restrict__ x, const int* __restrict__ idx,
    float* __restrict__ out) {
  const int w = blockIdx.x;
  const size_t bc = blockIdx.y;
  const int base = w * KWIN;
  const float* xs = x + bc * PN;
  float* ob = out + bc * PN + base;
  const int4* iv = (const int4*)(idx + base);

#pragma unroll
  for (int i = 0; i < 7; ++i) {
    const int g = i * 256 + (int)threadIdx.x;
    const int4 s = iv[g];
    f4v v;
    v.x = xs[s.x];
    v.y = xs[s.y];
    v.z = xs[s.z];
    v.w = xs[s.w];
    __builtin_nontemporal_store(v, (f4v*)(ob + (size_t)g * 4));
  }
}

extern "C" void kernel_launch(void* const* d_in, const int* in_sizes, int n_in,
                              void* d_out, int out_size, void* d_ws,
                              size_t ws_size, hipStream_t stream) {
  const float* x = (const float*)d_in[0];
  float* out = (float*)d_out;

  // Phase 1: pure-read prefetch of x into L3 (single-direction HBM).
  sweep_x<<<dim3(SWB), SWT, 0, stream>>>((const f4v*)x);

  if (g_perm.lds_ok) {
    // Phase 2: permute with L3-warm reads + pure NT write stream.
    dim3 grid(NWIN, NBC);  // (7, 384) = 2688 blocks
    clop_glds<<<grid, TPB, 0, stream>>>(x, g_perm.d_lofs, g_perm.d_ovf,
                                        g_perm.d_cnt, out);
    return;
  }

  const int* idx;
  if (g_perm.d_idx != nullptr) {
    idx = g_perm.d_idx;
  } else {
    (void)hipMemcpyAsync(d_ws, g_perm.h_idx.data(), PN * sizeof(int),
                         hipMemcpyHostToDevice, stream);
    idx = (const int*)d_ws;
  }
  dim3 grid(NWIN, NBC);
  clop_gather4<<<grid, 256, 0, stream>>>(x, idx, out);
}

// Round 9
// 133.487 us; speedup vs baseline: 1.0784x; 1.0784x over previous
//
#include <hip/hip_runtime.h>
#include <cstdint>
#include <cstring>
#include <vector>
#include <algorithm>

// CLOPLayer: out[b,c,k] = x[b,c, idx[k]], idx = seed-42-deterministic
// neighbor-swap permutation of the 224x224 grid (JAX threefry replicated
// bit-exactly on host at dlopen).
//
// R15: R14 (L3 prefetch sweep) regressed +10us: warm reads are fast in a
// copy-shaped kernel (R12 probe: 18us for the same 154MB) but slow inside
// the LDS-tile kernel -> the limiter is per-CU PHASE ALTERNATION, not HBM
// mixing: the per-block barrier makes each block burst reads, drain, burst
// writes; with only 4 resident blocks/CU the CU's issue stream alternates
// coarsely and uses its BW share at ~50% duty (339KB rd + 300KB wr at
// 24.6 GB/s/CU ~ 26us serialized ~ observed 39). Fix: 4x smaller tiles:
// 128-thr blocks, 8 output rows, halo 1 -> 9.5KB LDS -> 16 blocks/CU =
// 32 waves AND 16 independently-phased barriers per CU -> fine-grained
// read/write interleave (probe-like). Proven parts unchanged: glds stage,
// f2 interleaved emit, NT stores. Sweep dropped.

#define PH 224
#define PW 224
#define PN (PH * PW)   // 50176
#define NBC (128 * 3)  // 384 (b,c) slices

#define R_OUT 8                     // output rows per tile
#define NWIN (PH / R_OUT)           // 28 windows per slice
#define KWIN (R_OUT * PW)           // 1792 outputs per tile
#define TPB 128
#define EMIT_IT (KWIN / (2 * TPB))  // 7 float2 iterations per thread
#define OVF_CAP 192                 // per-window overflow slots (host-verified)

typedef float f4v __attribute__((ext_vector_type(4)));
typedef float f2v __attribute__((ext_vector_type(2)));

// ---------------------------------------------------------------------------
// Threefry-2x32, 20 rounds — bit-exact replica of jax/_src/prng.py lowering.
// ---------------------------------------------------------------------------
static inline uint32_t rotl32(uint32_t v, int d) {
  return (v << d) | (v >> (32 - d));
}

static void tf2x32(uint32_t k0, uint32_t k1, uint32_t x0, uint32_t x1,
                   uint32_t& o0, uint32_t& o1) {
  const uint32_t ks0 = k0, ks1 = k1, ks2 = k0 ^ k1 ^ 0x1BD11BDAu;
  uint32_t v0 = x0 + ks0;
  uint32_t v1 = x1 + ks1;
  static const int ra[4] = {13, 15, 26, 6};
  static const int rb[4] = {17, 29, 16, 24};
#define R4X(rr)                             \
  do {                                      \
    for (int _i = 0; _i < 4; ++_i) {        \
      v0 += v1;                             \
      v1 = rotl32(v1, (rr)[_i]);            \
      v1 ^= v0;                             \
    }                                       \
  } while (0)
  R4X(ra); v0 += ks1; v1 += ks2 + 1u;
  R4X(rb); v0 += ks2; v1 += ks0 + 2u;
  R4X(ra); v0 += ks0; v1 += ks1 + 3u;
  R4X(rb); v0 += ks1; v1 += ks2 + 4u;
  R4X(ra); v0 += ks2; v1 += ks0 + 5u;
#undef R4X
  o0 = v0;
  o1 = v1;
}

static void jax_split2(uint32_t k0, uint32_t k1,
                       uint32_t& a0, uint32_t& a1, uint32_t& b0, uint32_t& b1) {
  tf2x32(k0, k1, 0u, 0u, a0, a1);
  tf2x32(k0, k1, 0u, 1u, b0, b1);
}

static inline uint32_t jax_rb32(uint32_t k0, uint32_t k1, uint32_t i) {
  uint32_t y0, y1;
  tf2x32(k0, k1, 0u, i, y0, y1);
  return y0 ^ y1;  // partitionable random_bits: bits1 ^ bits2
}

// ---------------------------------------------------------------------------
// Host-side bit-exact replication of _index_permute(jax.random.key(42), ...)
// ---------------------------------------------------------------------------
static std::vector<int> compute_perm() {
  const int n = PN;
  const uint32_t K0 = 0u, K1 = 42u;  // jax.random.key(42)

  uint32_t k1a, k1b, k2a, k2b;
  jax_split2(K0, K1, k1a, k1b, k2a, k2b);

  // order = permutation(k1, n): 2 rounds of stable sort by random_bits.
  std::vector<int> order(n);
  for (int i = 0; i < n; ++i) order[i] = i;
  uint32_t ck0 = k1a, ck1 = k1b;
  std::vector<std::pair<uint32_t, int>> kv(n);
  for (int round = 0; round < 2; ++round) {
    uint32_t nk0, nk1, sk0, sk1;
    jax_split2(ck0, ck1, nk0, nk1, sk0, sk1);
    ck0 = nk0; ck1 = nk1;
    for (int i = 0; i < n; ++i) {
      kv[i] = {jax_rb32(sk0, sk1, (uint32_t)i), order[i]};
    }
    std::stable_sort(kv.begin(), kv.end(),
                     [](const std::pair<uint32_t, int>& a,
                        const std::pair<uint32_t, int>& b) {
                       return a.first < b.first;
                     });
    for (int i = 0; i < n; ++i) order[i] = kv[i].second;
  }

  // rs = choice(k2, 5, (n,), p): fp32 cumsum + uniform + searchsorted(left).
  float probs[5] = {(float)(1.0 - 0.3), (float)(0.3 / 4), (float)(0.3 / 4),
                    (float)(0.3 / 4), (float)(0.3 / 4)};
  float pc[5];
  pc[0] = probs[0];
  for (int i = 1; i < 5; ++i) pc[i] = pc[i - 1] + probs[i];

  std::vector<uint8_t> rs(n);
  for (int i = 0; i < n; ++i) {
    uint32_t bits = jax_rb32(k2a, k2b, (uint32_t)i);
    uint32_t fb = (bits >> 9) | 0x3f800000u;
    float u;
    std::memcpy(&u, &fb, 4);
    u -= 1.0f;
    if (u < 0.0f) u = 0.0f;
    float r = pc[4] * (1.0f - u);
    int ind = (int)(std::lower_bound(pc, pc + 5, r) - pc);
    rs[i] = (uint8_t)ind;
  }

  // Sequential swap scan.
  std::vector<int> idx(n);
  for (int i = 0; i < n; ++i) idx[i] = i;
  for (int t = 0; t < n; ++t) {
    const int id = order[t];
    const int r = rs[t];
    const int i = id / PW, j = id % PW;
    int ip = i, jp = j;
    if (r == 1)      ip = (i + 1) % PH;
    else if (r == 2) ip = (i - 1 + PH) % PH;
    else if (r == 3) jp = (j + 1) % PW;
    else if (r == 4) jp = (j - 1 + PW) % PW;
    const int id2 = (r == 0) ? id : (ip * PW + jp);
    const int a = idx[id];
    const int b = idx[id2];
    idx[id]  = b;
    idx[id2] = a;
  }
  return idx;
}

// Build per-window LDS offset tables for given halo. Sources beyond the halo
// go to a per-window overflow list (staged into LDS spill at SR*PW + o).
// Returns false iff any window overflows OVF_CAP.
static bool build_tables(const std::vector<int>& idx, int halo,
                         std::vector<uint16_t>& lofs, std::vector<int>& ovf,
                         std::vector<int>& cnt) {
  const int sr = R_OUT + 2 * halo;
  lofs.assign((size_t)NWIN * KWIN, 0);
  ovf.assign((size_t)NWIN * OVF_CAP, 0);
  cnt.assign(NWIN, 0);
  for (int w = 0; w < NWIN; ++w) {
    const int g0 = w * R_OUT - halo;
    int no = 0;
    for (int kk = 0; kk < KWIN; ++kk) {
      const int k = w * KWIN + kk;
      const int s = idx[k];
      const int srow = s / PW, scol = s % PW;
      int i = ((srow - g0) % PH + PH) % PH;
      if (i < sr) {
        lofs[(size_t)w * KWIN + kk] = (uint16_t)(i * PW + scol);
      } else {
        if (no >= OVF_CAP) return false;
        ovf[(size_t)w * OVF_CAP + no] = s;
        lofs[(size_t)w * KWIN + kk] = (uint16_t)(sr * PW + no);
        ++no;
      }
    }
    cnt[w] = no;
  }
  return true;
}

// Load-time init (legal: runs at dlopen, before graph capture).
struct PermHolder {
  std::vector<int> h_idx;
  int* d_idx = nullptr;
  uint16_t* d_lofs = nullptr;
  int* d_ovf = nullptr;
  int* d_cnt = nullptr;
  int halo = 0;  // 1 or 2 => small-tile LDS path; 0 => gather fallback

  PermHolder() {
    h_idx = compute_perm();

    int* p = nullptr;
    if (hipMalloc(&p, PN * sizeof(int)) == hipSuccess &&
        hipMemcpy(p, h_idx.data(), PN * sizeof(int),
                  hipMemcpyHostToDevice) == hipSuccess) {
      d_idx = p;
    }

    for (int h : {1, 2}) {
      std::vector<uint16_t> lofs;
      std::vector<int> ovf, cnt;
      if (!build_tables(h_idx, h, lofs, ovf, cnt)) continue;
      uint16_t* ql = nullptr;
      int* qo = nullptr;
      int* qc = nullptr;
      bool ok =
          hipMalloc(&ql, lofs.size() * sizeof(uint16_t)) == hipSuccess &&
          hipMemcpy(ql, lofs.data(), lofs.size() * sizeof(uint16_t),
                    hipMemcpyHostToDevice) == hipSuccess &&
          hipMalloc(&qo, ovf.size() * sizeof(int)) == hipSuccess &&
          hipMemcpy(qo, ovf.data(), ovf.size() * sizeof(int),
                    hipMemcpyHostToDevice) == hipSuccess &&
          hipMalloc(&qc, cnt.size() * sizeof(int)) == hipSuccess &&
          hipMemcpy(qc, cnt.data(), cnt.size() * sizeof(int),
                    hipMemcpyHostToDevice) == hipSuccess;
      if (ok) {
        d_lofs = ql;
        d_ovf = qo;
        d_cnt = qc;
        halo = h;
        break;
      }
    }
  }
};
static PermHolder g_perm;

// ---------------------------------------------------------------------------
// Small-tile LDS permute. blockIdx.x = window (28), blockIdx.y = bc (384).
// 128 threads; halo1: 10 rows staged = 9.5KB LDS -> 16 blocks/CU (32 waves,
// 16 independent barrier phases). glds fire-and-forget stage; f2 interleaved
// emit (8B lane stride, 2-way banks = free); NT stores.
// ---------------------------------------------------------------------------
template <int HALO_T>
__global__ __launch_bounds__(TPB) void clop_small(
    const float* __restrict__ x, const uint16_t* __restrict__ lofs,
    const int* __restrict__ ovf_idx, const int* __restrict__ ovf_cnt,
    float* __restrict__ out) {
  constexpr int SR = R_OUT + 2 * HALO_T;
  constexpr int STAGE = SR * (PW / 4);            // f4 loads
  constexpr int SITER = (STAGE + TPB - 1) / TPB;  // 5 (halo1) / 6 (halo2)
  __shared__ float tile[SR * PW + OVF_CAP];

  const int w = blockIdx.x;
  const size_t bc = blockIdx.y;
  const int g0 = w * R_OUT - HALO_T;
  const float* xs = x + bc * PN;

  // Stage: SR toroidal rows, dense f4 glds (async, no VGPR round-trip).
#pragma unroll
  for (int i = 0; i < SITER; ++i) {
    const int t = (int)threadIdx.x + i * TPB;
    if (t < STAGE) {
      const int r = t / (PW / 4);
      const int j = (t % (PW / 4)) * 4;
      int g = g0 + r;
      if (g < 0) g += PH;
      else if (g >= PH) g -= PH;
      __builtin_amdgcn_global_load_lds(
          (const __attribute__((address_space(1))) void*)(xs + g * PW + j),
          (__attribute__((address_space(3))) void*)(tile + (size_t)t * 4),
          16, 0, 0);
    }
  }

  // Emit-offset prefetch (independent; overlaps glds latency).
  const uint32_t* lw2 = (const uint32_t*)(lofs + (size_t)w * KWIN);
  uint32_t o2[EMIT_IT];
#pragma unroll
  for (int i = 0; i < EMIT_IT; ++i)
    o2[i] = lw2[i * TPB + (int)threadIdx.x];

  // Overflow spill: rare far-movers, 4B glds into LDS slots.
  const int novf = ovf_cnt[w];
  for (int t = (int)threadIdx.x; t < novf; t += TPB) {
    const int s = ovf_idx[w * OVF_CAP + t];
    __builtin_amdgcn_global_load_lds(
        (const __attribute__((address_space(1))) void*)(xs + s),
        (__attribute__((address_space(3))) void*)(tile + SR * PW + t), 4, 0,
        0);
  }

  __syncthreads();  // 2-wave barrier; drains this block's glds

  // Emit: 7 x float2 interleaved per thread; dense NT stores.
  float* ob = out + bc * PN + (size_t)w * KWIN;
#pragma unroll
  for (int i = 0; i < EMIT_IT; ++i) {
    const uint32_t o = o2[i];
    f2v v;
    v.x = tile[o & 0xFFFFu];
    v.y = tile[o >> 16];
    __builtin_nontemporal_store(
        v, (f2v*)(ob + i * (2 * TPB) + 2 * (int)threadIdx.x));
  }
}

// ---------------------------------------------------------------------------
// Fallback (proven-correct R10 kernel): copy-structured f4 gather.
// ---------------------------------------------------------------------------
__global__ __launch_bounds__(256) void clop_gather4(
    const float* __restrict__ x, const int* __restrict__ idx,
    float* __restrict__ out) {
  const int w = blockIdx.x;
  const size_t bc = blockIdx.y;
  const int base = w * (PN / 7);
  const float* xs = x + bc * PN;
  float* ob = out + bc * PN + base;
  const int4* iv = (const int4*)(idx + base);

#pragma unroll
  for (int i = 0; i < 7; ++i) {
    const int g = i * 256 + (int)threadIdx.x;
    const int4 s = iv[g];
    f4v v;
    v.x = xs[s.x];
    v.y = xs[s.y];
    v.z = xs[s.z];
    v.w = xs[s.w];
    __builtin_nontemporal_store(v, (f4v*)(ob + (size_t)g * 4));
  }
}

extern "C" void kernel_launch(void* const* d_in, const int* in_sizes, int n_in,
                              void* d_out, int out_size, void* d_ws,
                              size_t ws_size, hipStream_t stream) {
  const float* x = (const float*)d_in[0];
  float* out = (float*)d_out;

  if (g_perm.halo == 1) {
    dim3 grid(NWIN, NBC);  // (28, 384) = 10752 blocks
    clop_small<1><<<grid, TPB, 0, stream>>>(x, g_perm.d_lofs, g_perm.d_ovf,
                                            g_perm.d_cnt, out);
    return;
  }
  if (g_perm.halo == 2) {
    dim3 grid(NWIN, NBC);
    clop_small<2><<<grid, TPB, 0, stream>>>(x, g_perm.d_lofs, g_perm.d_ovf,
                                            g_perm.d_cnt, out);
    return;
  }

  const int* idx;
  if (g_perm.d_idx != nullptr) {
    idx = g_perm.d_idx;
  } else {
    (void)hipMemcpyAsync(d_ws, g_perm.h_idx.data(), PN * sizeof(int),
                         hipMemcpyHostToDevice, stream);
    idx = (const int*)d_ws;
  }
  dim3 grid(7, NBC);
  clop_gather4<<<grid, 256, 0, stream>>>(x, idx, out);
}